// Round 7
// baseline (1125.040 us; speedup 1.0000x reference)
//
#include <hip/hip_runtime.h>
#include <hip/hip_bf16.h>

// ---------------------------------------------------------------------------
// Round 6 == Round 5 resubmitted (round-5 bench died at infra level; source
// audited for OOB/hangs — none found; ws 50.8 MB < proven 59 MB bound).
// Design: deforms are round-1-pure (fp32 offsets, NCHW sampling, single
// coalesced store). All layout conversion in dedicated pad kernels.
//  - conv (MFMA implicit GEMM, NHWC bf16 in) -> fp32 NCHW offset planes
//  - deform1: fp32 fr/ft -> bf16 NCHW A1;  deform2/3: bf16 NCHW -> bf16 NCHW
//  - deform4: fp32 ft -> fp32 out
//  - padA: bf16 NCHW -> padded NHWC bf16 (next conv's B operand)
// ---------------------------------------------------------------------------

#define HH 96
#define WW 96
#define HWSZ (HH * WW)
#define BB 8
#define PW 98
#define PP (PW * PW)

using bf16x8 = __attribute__((ext_vector_type(8))) short;
using f32x4  = __attribute__((ext_vector_type(4))) float;

__device__ __forceinline__ unsigned int f2bf(float f) {
    __hip_bfloat16 h = __float2bfloat16(f);
    return (unsigned int)*reinterpret_cast<unsigned short*>(&h);
}
__device__ __forceinline__ float bf2f(unsigned short u) {
    return __uint_as_float(((unsigned int)u) << 16);
}

// ---- weight prepack: fp32 [outC][C][3][3] -> bf16 A-frags [mt][ks][lane][8], k=t*C+c
__global__ void prepack_w_kernel(const float* __restrict__ w, short* __restrict__ wp,
                                 int outC, int C, int MT, int KS) {
    int i = blockIdx.x * 256 + threadIdx.x;
    if (i >= MT * KS * 64) return;
    int lane = i & 63;
    int s = (i >> 6) % KS;
    int m = (i >> 6) / KS;
    int oc = m * 16 + (lane & 15);
    short v[8];
#pragma unroll
    for (int j = 0; j < 8; ++j) {
        int k = s * 32 + (lane >> 4) * 8 + j;
        int t = k / C, c = k % C;
        float f = (oc < outC) ? w[((size_t)oc * C + c) * 9 + t] : 0.f;
        v[j] = (short)f2bf(f);
    }
    *reinterpret_cast<bf16x8*>(wp + (size_t)i * 8) = *reinterpret_cast<bf16x8*>(v);
}

// ---- pad fp32 NCHW 64ch -> [b][98][98][64] bf16 (borders zeroed)
__global__ void pad_nhwc64_kernel(const float* __restrict__ src,
                                  __hip_bfloat16* __restrict__ out) {
    int i = blockIdx.x * 256 + threadIdx.x;
    if (i >= BB * PP) return;
    int px = i % PW, py = (i / PW) % PW, b = i / PP;
    unsigned int* op = reinterpret_cast<unsigned int*>(out + (size_t)i * 64);
    if (px == 0 || px == PW - 1 || py == 0 || py == PW - 1) {
#pragma unroll
        for (int c = 0; c < 32; ++c) op[c] = 0u;
        return;
    }
    const float* sp = src + (size_t)b * 64 * HWSZ + (py - 1) * WW + (px - 1);
#pragma unroll 8
    for (int c = 0; c < 32; ++c)
        op[c] = f2bf(sp[(size_t)(2 * c) * HWSZ]) | (f2bf(sp[(size_t)(2 * c + 1) * HWSZ]) << 16);
}

// ---- pad bf16 NCHW 64ch -> [b][98][98][64] bf16 (borders zeroed)
__global__ void padA_kernel(const __hip_bfloat16* __restrict__ src,
                            __hip_bfloat16* __restrict__ out) {
    int i = blockIdx.x * 256 + threadIdx.x;
    if (i >= BB * PP) return;
    int px = i % PW, py = (i / PW) % PW, b = i / PP;
    unsigned int* op = reinterpret_cast<unsigned int*>(out + (size_t)i * 64);
    if (px == 0 || px == PW - 1 || py == 0 || py == PW - 1) {
#pragma unroll
        for (int c = 0; c < 32; ++c) op[c] = 0u;
        return;
    }
    const unsigned short* sp = reinterpret_cast<const unsigned short*>(src)
        + (size_t)b * 64 * HWSZ + (py - 1) * WW + (px - 1);
#pragma unroll 8
    for (int c = 0; c < 32; ++c)
        op[c] = (unsigned int)sp[(size_t)(2 * c) * HWSZ]
              | ((unsigned int)sp[(size_t)(2 * c + 1) * HWSZ] << 16);
}

// ---- MFMA implicit-GEMM 3x3 conv; out = fp32 NCHW offset planes -----------
// xa: channels 0..63, xb: channels 64..127 (same pointer for C=64).
template <int C>
__global__ __launch_bounds__(256) void conv3_mfma_kernel(
    const __hip_bfloat16* __restrict__ xa,
    const __hip_bfloat16* __restrict__ xb,
    const short* __restrict__ wp,
    float* __restrict__ offb, int outC) {
    constexpr int KS = 9 * C / 32;
    int lane = threadIdx.x & 63;
    int wave = threadIdx.x >> 6;
    int y = blockIdx.x * 4 + wave;
    int m = blockIdx.y;
    int b = blockIdx.z;
    int l15 = lane & 15, lhi = lane >> 4;

    f32x4 acc[6];
#pragma unroll
    for (int nt = 0; nt < 6; ++nt) acc[nt] = (f32x4){0.f, 0.f, 0.f, 0.f};

    const short* wpm = wp + ((size_t)m * KS) * 64 * 8 + (size_t)lane * 8;

#pragma unroll 3
    for (int s = 0; s < KS; ++s) {
        bf16x8 afrag = *reinterpret_cast<const bf16x8*>(wpm + (size_t)s * 64 * 8);
        int t  = (s * 32) / C;
        int cb = (s * 32) % C;
        const __hip_bfloat16* xp = (cb < 64) ? xa : xb;
        int c0 = (cb & 63) + lhi * 8;
        int ky = t / 3, kx = t % 3;
        const short* bbase = reinterpret_cast<const short*>(xp)
            + (((size_t)b * PW + (y + ky)) * PW + kx + l15) * 64 + c0;
#pragma unroll
        for (int nt = 0; nt < 6; ++nt) {
            bf16x8 bfrag = *reinterpret_cast<const bf16x8*>(bbase + (size_t)nt * 16 * 64);
            acc[nt] = __builtin_amdgcn_mfma_f32_16x16x32_bf16(afrag, bfrag, acc[nt], 0, 0, 0);
        }
    }

    int ocb = m * 16 + lhi * 4;
#pragma unroll
    for (int nt = 0; nt < 6; ++nt) {
        int pix = y * WW + nt * 16 + l15;
#pragma unroll
        for (int r = 0; r < 4; ++r) {
            int oc = ocb + r;
            if (oc < outC)
                offb[((size_t)b * outC + oc) * HWSZ + pix] = acc[nt][r];
        }
    }
}

// ---- deformable conv: fp32 offsets, NCHW-plane sampling, single store -----
// SRCBF: source planes are bf16 (else fp32). DSTBF: store bf16 NCHW A-buffer
// (else fp32 NCHW outp). xA: channels 0..63, xB: 64..127.
template <int CG, int OCG, int OFFC, bool SRCBF, bool DSTBF>
__global__ __launch_bounds__(256) void deform5_kernel(
    const void* __restrict__ xA, const void* __restrict__ xB,
    const float* __restrict__ offb,
    const float* __restrict__ w,
    const float* __restrict__ bias,
    __hip_bfloat16* __restrict__ anchw,
    float* __restrict__ outp) {
    int pix = blockIdx.x * 256 + threadIdx.x;
    int g   = blockIdx.y;
    int b   = blockIdx.z;
    int x = pix % WW, y = pix / WW;

    const float* offp = offb + ((size_t)b * OFFC + g * 18) * HWSZ + pix;

    float bw0[9], bw1[9], bw2[9], bw3[9];
    int   bi0[9], bi1[9], bi2[9], bi3[9];
#pragma unroll
    for (int k = 0; k < 9; ++k) {
        int ky = k / 3, kx = k % 3;
        float offy = offp[(size_t)(2 * k + 0) * HWSZ];
        float offx = offp[(size_t)(2 * k + 1) * HWSZ];
        float py = offy + (float)(y - 1 + ky);
        float px = offx + (float)(x - 1 + kx);
        float fy0 = floorf(py), fx0 = floorf(px);
        float wy = py - fy0, wx = px - fx0;
        int y0 = (int)fy0, x0 = (int)fx0;
        int y1 = y0 + 1,  x1 = x0 + 1;
        bool vy0 = (y0 >= 0) && (y0 < HH);
        bool vy1 = (y1 >= 0) && (y1 < HH);
        bool vx0 = (x0 >= 0) && (x0 < WW);
        bool vx1 = (x1 >= 0) && (x1 < WW);
        int cy0 = min(max(y0, 0), HH - 1), cy1 = min(max(y1, 0), HH - 1);
        int cx0 = min(max(x0, 0), WW - 1), cx1 = min(max(x1, 0), WW - 1);
        bw0[k] = (1.f - wy) * (1.f - wx) * ((vy0 && vx0) ? 1.f : 0.f);
        bw1[k] = (1.f - wy) * wx         * ((vy0 && vx1) ? 1.f : 0.f);
        bw2[k] = wy * (1.f - wx)         * ((vy1 && vx0) ? 1.f : 0.f);
        bw3[k] = wy * wx                 * ((vy1 && vx1) ? 1.f : 0.f);
        bi0[k] = cy0 * WW + cx0;  bi1[k] = cy0 * WW + cx1;
        bi2[k] = cy1 * WW + cx0;  bi3[k] = cy1 * WW + cx1;
    }

    float acc[OCG];
#pragma unroll
    for (int o = 0; o < OCG; ++o) acc[o] = bias[g * OCG + o];

    int gc = g * CG;
    const void* srcv = (gc < 64) ? xA : xB;
    size_t pbase = (size_t)b * 64 + (size_t)((gc < 64) ? gc : gc - 64);

    for (int c = 0; c < CG; ++c) {
        float v[9];
        if constexpr (SRCBF) {
            const unsigned short* p = (const unsigned short*)srcv + (pbase + c) * HWSZ;
#pragma unroll
            for (int k = 0; k < 9; ++k)
                v[k] = bw0[k] * bf2f(p[bi0[k]]) + bw1[k] * bf2f(p[bi1[k]])
                     + bw2[k] * bf2f(p[bi2[k]]) + bw3[k] * bf2f(p[bi3[k]]);
        } else {
            const float* p = (const float*)srcv + (pbase + c) * HWSZ;
#pragma unroll
            for (int k = 0; k < 9; ++k)
                v[k] = bw0[k] * p[bi0[k]] + bw1[k] * p[bi1[k]]
                     + bw2[k] * p[bi2[k]] + bw3[k] * p[bi3[k]];
        }
        const float* wc = w + ((size_t)(g * OCG) * CG + c) * 9;
#pragma unroll
        for (int o = 0; o < OCG; ++o) {
            const float* wo = wc + (size_t)o * CG * 9;
#pragma unroll
            for (int k = 0; k < 9; ++k) acc[o] = fmaf(v[k], wo[k], acc[o]);
        }
    }

    if constexpr (DSTBF) {
#pragma unroll
        for (int o = 0; o < OCG; ++o)
            *reinterpret_cast<unsigned short*>(
                anchw + ((size_t)b * 64 + g * OCG + o) * HWSZ + pix) =
                (unsigned short)f2bf(acc[o]);
    } else {
        float* op = outp + ((size_t)b * 64 + g * OCG) * HWSZ + pix;
#pragma unroll
        for (int o = 0; o < OCG; ++o) op[(size_t)o * HWSZ] = acc[o];
    }
}

extern "C" void kernel_launch(void* const* d_in, const int* in_sizes, int n_in,
                              void* d_out, int out_size, void* d_ws, size_t ws_size,
                              hipStream_t stream) {
    const float* fr     = (const float*)d_in[0];
    const float* ft     = (const float*)d_in[1];
    const float* off1_w = (const float*)d_in[2];
    const float* def1_w = (const float*)d_in[3];
    const float* def1_b = (const float*)d_in[4];
    const float* off2_w = (const float*)d_in[5];
    const float* def2_w = (const float*)d_in[6];
    const float* def2_b = (const float*)d_in[7];
    const float* off3_w = (const float*)d_in[8];
    const float* def3_w = (const float*)d_in[9];
    const float* def3_b = (const float*)d_in[10];
    const float* off4_w = (const float*)d_in[11];
    const float* def4_w = (const float*)d_in[12];
    const float* def4_b = (const float*)d_in[13];
    float* outp = (float*)d_out;

    // ---- workspace layout (~50.8 MB; proven bound ws_size >= 59.0 MB) ----
    char* ws = (char*)d_ws;
    const size_t offb_sz = (size_t)BB * 72 * HWSZ * 4;   // 21.2 MB fp32
    const size_t a_sz    = (size_t)BB * 64 * HWSZ * 2;   //  9.44 MB bf16 NCHW
    const size_t p_sz    = (size_t)BB * PP * 64 * 2;     //  9.83 MB bf16 NHWC padded
    float*          offb = (float*)ws;          ws += offb_sz;
    __hip_bfloat16* A1   = (__hip_bfloat16*)ws; ws += a_sz;
    __hip_bfloat16* P0   = (__hip_bfloat16*)ws; ws += p_sz;
    __hip_bfloat16* P1   = (__hip_bfloat16*)ws; ws += p_sz;   // also A2 (after conv1)
    short* wp1 = (short*)ws; ws += (size_t)5 * 36 * 64 * 8 * 2;
    short* wp2 = (short*)ws; ws += (size_t)5 * 18 * 64 * 8 * 2;
    short* wp3 = (short*)ws; ws += (size_t)5 * 18 * 64 * 8 * 2;
    short* wp4 = (short*)ws; ws += (size_t)3 * 18 * 64 * 8 * 2;
    __hip_bfloat16* A2 = P1;   // P1 free after conv1

    dim3 blk(256);
    int padBlocks = (BB * PP + 255) / 256;

    prepack_w_kernel<<<(5 * 36 * 64 + 255) / 256, blk, 0, stream>>>(off1_w, wp1, 72, 128, 5, 36);
    prepack_w_kernel<<<(5 * 18 * 64 + 255) / 256, blk, 0, stream>>>(off2_w, wp2, 72, 64, 5, 18);
    prepack_w_kernel<<<(5 * 18 * 64 + 255) / 256, blk, 0, stream>>>(off3_w, wp3, 72, 64, 5, 18);
    prepack_w_kernel<<<(3 * 18 * 64 + 255) / 256, blk, 0, stream>>>(off4_w, wp4, 36, 64, 3, 18);

    pad_nhwc64_kernel<<<padBlocks, blk, 0, stream>>>(fr, P0);
    pad_nhwc64_kernel<<<padBlocks, blk, 0, stream>>>(ft, P1);

    dim3 gDefG4(36, 4, BB), gDefG2(36, 2, BB);

    // ---- block 1: conv(fr|ft NHWC) -> offb fp32; deform samples fp32 fr/ft -> A1
    conv3_mfma_kernel<128><<<dim3(24, 5, BB), blk, 0, stream>>>(P0, P1, wp1, offb, 72);
    deform5_kernel<32, 16, 72, false, true><<<gDefG4, blk, 0, stream>>>(
        fr, ft, offb, def1_w, def1_b, A1, nullptr);

    // ---- block 2: padA1 -> P0; conv(P0) -> offb; deform samples A1 -> A2
    padA_kernel<<<padBlocks, blk, 0, stream>>>(A1, P0);
    conv3_mfma_kernel<64><<<dim3(24, 5, BB), blk, 0, stream>>>(P0, P0, wp2, offb, 72);
    deform5_kernel<16, 16, 72, true, true><<<gDefG4, blk, 0, stream>>>(
        A1, A1, offb, def2_w, def2_b, A2, nullptr);

    // ---- block 3: padA2 -> P0; conv(P0) -> offb; deform samples A2 -> A1
    padA_kernel<<<padBlocks, blk, 0, stream>>>(A2, P0);
    conv3_mfma_kernel<64><<<dim3(24, 5, BB), blk, 0, stream>>>(P0, P0, wp3, offb, 72);
    deform5_kernel<16, 16, 72, true, true><<<gDefG4, blk, 0, stream>>>(
        A2, A2, offb, def3_w, def3_b, A1, nullptr);

    // ---- block 4: padA1 -> P0; conv(P0) -> offb(36); deform samples fp32 ft -> out
    padA_kernel<<<padBlocks, blk, 0, stream>>>(A1, P0);
    conv3_mfma_kernel<64><<<dim3(24, 3, BB), blk, 0, stream>>>(P0, P0, wp4, offb, 36);
    deform5_kernel<32, 32, 36, false, false><<<gDefG2, blk, 0, stream>>>(
        ft, ft, offb, def4_w, def4_b, nullptr, outp);
}